// Round 6
// baseline (274.271 us; speedup 1.0000x reference)
//
#include <hip/hip_runtime.h>
#include <stdint.h>

#define BN 4096      // N = H*W
#define NCH 256      // C
#define DQ 32        // D = C/8

typedef _Float16 half8  __attribute__((ext_vector_type(8)));
typedef _Float16 half4  __attribute__((ext_vector_type(4)));
typedef float   floatx4  __attribute__((ext_vector_type(4)));
typedef float   floatx16 __attribute__((ext_vector_type(16)));

typedef __attribute__((address_space(1))) const void g1_void;
typedef __attribute__((address_space(3))) void l3_void;

#define LOG2E 1.44269504088896f
#define EXP2F(x) __builtin_amdgcn_exp2f(x)

// ---------------------------------------------------------------------------
// convert_w: cast Wq|Wk|Wv (fp32) into one concatenated f16 buffer.
// Wk is pre-scaled by log2(e) so S-scores land in the exp2 domain.
// layout: [0..8191]=Wq, [8192..16383]=Wk*log2e, [16384..81919]=Wv. grid 80x256.
// ---------------------------------------------------------------------------
__global__ __launch_bounds__(256) void convert_w(
    const float* __restrict__ Wq, const float* __restrict__ Wk,
    const float* __restrict__ Wv, _Float16* __restrict__ W16)
{
    int e4 = (blockIdx.x * 256 + threadIdx.x) * 4;
    float4 v;
    if (e4 < 8192)        v = *(const float4*)&Wq[e4];
    else if (e4 < 16384) {
        v = *(const float4*)&Wk[e4 - 8192];
        v.x *= LOG2E; v.y *= LOG2E; v.z *= LOG2E; v.w *= LOG2E;
    }
    else                  v = *(const float4*)&Wv[e4 - 16384];
    half4 h = { (_Float16)v.x, (_Float16)v.y, (_Float16)v.z, (_Float16)v.w };
    *(half4*)&W16[e4] = h;
}

// ---------------------------------------------------------------------------
// MFMA projection (unchanged from R4 except bk scaled by log2e).
// ---------------------------------------------------------------------------
__global__ __launch_bounds__(512) void proj_kernel(
    const float* __restrict__ x, const _Float16* __restrict__ W16,
    const float* __restrict__ bq, const float* __restrict__ bk,
    const float* __restrict__ bv,
    _Float16* __restrict__ qT, _Float16* __restrict__ kT,
    _Float16* __restrict__ vb)
{
    const int t  = threadIdx.x;
    const int n0 = blockIdx.x * 128;
    const int b  = blockIdx.y;

    __shared__ __align__(16) _Float16 xTl[128 * 256];  // 64 KB

#pragma unroll
    for (int p = 0; p < 2; ++p) {
        const int kb = p * 128 + (t >> 5) * 8;
        const int n4 = (t & 31) * 4;
        float4 xr[8];
#pragma unroll
        for (int i = 0; i < 8; ++i)
            xr[i] = *(const float4*)&x[((size_t)b * NCH + kb + i) * BN + n0 + n4];
        const float* xf = (const float*)xr;
#pragma unroll
        for (int j = 0; j < 4; ++j) {
            const int n = n4 + j;
            half8 hv;
#pragma unroll
            for (int i = 0; i < 8; ++i) hv[i] = (_Float16)xf[i * 4 + j];
            const int phys = (kb >> 3) ^ ((n >> 2) & 31);
            *(half8*)&xTl[n * 256 + phys * 8] = hv;
        }
    }
    __syncthreads();

    const int lane  = t & 63;
    const int w     = t >> 6;
    const int col32 = lane & 31;
    const int h     = lane >> 5;
    const int nc    = w & 3;
    const int job   = w >> 2;

    const _Float16* Wq16 = W16;
    const _Float16* Wk16 = W16 + 8192;
    const _Float16* Wv16 = W16 + 16384;

#define XFRAG(ks) (*(const half8*)&xTl[(nc * 32 + col32) * 256 + \
        (((ks) * 2 + h) ^ (((nc * 32 + col32) >> 2) & 31)) * 8])

    if (job == 0) {
        const float bqv = bq[col32];
        const float bkv = bk[col32] * LOG2E;
        floatx16 aq, ak2;
#pragma unroll
        for (int r = 0; r < 16; ++r) { aq[r] = 0.0f; ak2[r] = 0.0f; }
#pragma unroll
        for (int ks = 0; ks < 16; ++ks) {
            half8 xa = XFRAG(ks);
            half8 wqf = *(const half8*)&Wq16[col32 * 256 + ks * 16 + h * 8];
            half8 wkf = *(const half8*)&Wk16[col32 * 256 + ks * 16 + h * 8];
            aq  = __builtin_amdgcn_mfma_f32_32x32x16_f16(xa, wqf, aq, 0, 0, 0);
            ak2 = __builtin_amdgcn_mfma_f32_32x32x16_f16(xa, wkf, ak2, 0, 0, 0);
        }
#pragma unroll
        for (int r = 0; r < 16; ++r) {
            const int n = n0 + nc * 32 + (r & 3) + 8 * (r >> 2) + 4 * h;
            qT[((size_t)b * BN + n) * DQ + col32] = (_Float16)(aq[r] + bqv);
            kT[((size_t)b * BN + n) * DQ + col32] = (_Float16)(ak2[r] + bkv);
        }
    }

    const int rg_lo = (job == 0) ? 0 : 3;
    const int rg_hi = (job == 0) ? 3 : 8;
    for (int rg = rg_lo; rg < rg_hi; ++rg) {
        floatx16 av;
#pragma unroll
        for (int r = 0; r < 16; ++r) av[r] = 0.0f;
#pragma unroll
        for (int ks = 0; ks < 16; ++ks) {
            half8 xb  = XFRAG(ks);
            half8 wvf = *(const half8*)&Wv16[(rg * 32 + col32) * 256 + ks * 16 + h * 8];
            av = __builtin_amdgcn_mfma_f32_32x32x16_f16(wvf, xb, av, 0, 0, 0);
        }
#pragma unroll
        for (int r = 0; r < 16; ++r) {
            const int c = rg * 32 + (r & 3) + 8 * (r >> 2) + 4 * h;
            vb[((size_t)b * NCH + c) * BN + n0 + nc * 32 + col32] =
                (_Float16)(av[r] + bv[c]);
        }
    }
#undef XFRAG
}

// ---------------------------------------------------------------------------
// MFMA flash attention, single-barrier pipelined K-loop.
// grid (N/64, 2, B), block 256 (4 waves). 64 iters x 32 keys.
// vs double-buffered ([2][256 c][32 m], 64B rows, seg^((c>>1)&3) swizzle);
// Ps/alph double-buffered. One __syncthreads per iter; V/K prefetch for
// iter i+1 issued right AFTER the barrier -> stays in flight across PV+S.
// Scores arrive in exp2 domain (Wk pre-scaled).
// ---------------------------------------------------------------------------
__global__ __launch_bounds__(256, 3) void flash_kernel(
    const _Float16* __restrict__ qT, const _Float16* __restrict__ kT,
    const _Float16* __restrict__ vb,
    _Float16* __restrict__ Op, float* __restrict__ Ml)
{
    const int t    = threadIdx.x;
    const int lane = t & 63;
    const int w    = t >> 6;
    const int n0   = blockIdx.x * 64;
    const int kh   = blockIdx.y;
    const int b    = blockIdx.z;
    const int kbase = kh * 2048;

    __shared__ __align__(16) _Float16 vs[2][NCH * 32];  // 2 x 16 KB
    __shared__ __align__(16) _Float16 Ps[2][64 * 32];   // 2 x 4 KB
    __shared__ float alph_s[2][64];

    const int col   = lane & 15;
    const int q4    = lane >> 4;
    const int col32 = lane & 31;
    const int h     = lane >> 5;

    const _Float16* kp = kT + (size_t)b * BN * DQ;
    const _Float16* vp = vb + (size_t)b * NCH * BN;

    // persistent B_Q frag
    half8 bqf = *(const half8*)&qT[((size_t)b * BN + n0 + w * 16 + col) * DQ + q4 * 8];

    floatx16 acc[2][2];
#pragma unroll
    for (int ct = 0; ct < 2; ++ct)
#pragma unroll
        for (int nt = 0; nt < 2; ++nt)
#pragma unroll
            for (int r = 0; r < 16; ++r) acc[ct][nt][r] = 0.0f;

    float m_i = -1e30f, l_i = 0.0f;

    // V staging geometry: per call 64 lanes x 16B = 16 rows x 64B
    const int vrow_l = lane >> 2;                       // 0..15 row within call
    // prologue: V0 -> vs[0], K0 -> regs
#pragma unroll
    for (int j = 0; j < 4; ++j) {
        const int c = w * 64 + j * 16 + vrow_l;
        const int s_log = (lane & 3) ^ ((c >> 1) & 3);
        __builtin_amdgcn_global_load_lds(
            (g1_void*)&vp[(size_t)c * BN + kbase + s_log * 8],
            (l3_void*)&vs[0][(w * 64 + j * 16) * 32], 16, 0, 0);
    }
    half8 ak[2];
#pragma unroll
    for (int mt = 0; mt < 2; ++mt)
        ak[mt] = *(const half8*)&kp[(size_t)(kbase + mt * 16 + col) * DQ + q4 * 8];

    for (int it = 0; it < 64; ++it) {
        const int cur = it & 1;
        const int mc  = kbase + it * 32;

        // ---- S = K^T Q (exp2 domain) ----
        floatx4 sf[2];
#pragma unroll
        for (int mt = 0; mt < 2; ++mt) {
            floatx4 z = { 0.0f, 0.0f, 0.0f, 0.0f };
            sf[mt] = __builtin_amdgcn_mfma_f32_16x16x32_f16(ak[mt], bqf, z, 0, 0, 0);
        }

        // ---- online softmax stats ----
        float cmax = fmaxf(fmaxf(fmaxf(sf[0][0], sf[0][1]), fmaxf(sf[0][2], sf[0][3])),
                           fmaxf(fmaxf(sf[1][0], sf[1][1]), fmaxf(sf[1][2], sf[1][3])));
        cmax = fmaxf(cmax, __shfl_xor(cmax, 16));
        cmax = fmaxf(cmax, __shfl_xor(cmax, 32));
        float mn = fmaxf(m_i, cmax);
        float al = EXP2F(m_i - mn);
        float csum = 0.0f;
        half4 pk[2];
#pragma unroll
        for (int mt = 0; mt < 2; ++mt) {
            float p0 = EXP2F(sf[mt][0] - mn);
            float p1 = EXP2F(sf[mt][1] - mn);
            float p2 = EXP2F(sf[mt][2] - mn);
            float p3 = EXP2F(sf[mt][3] - mn);
            csum += p0 + p1 + p2 + p3;
            pk[mt] = (half4){ (_Float16)p0, (_Float16)p1, (_Float16)p2, (_Float16)p3 };
        }
        csum += __shfl_xor(csum, 16);
        csum += __shfl_xor(csum, 32);
        l_i = l_i * al + csum;
        m_i = mn;

        // ---- write Ps[cur] (seg16 ^ ((n>>1)&3) swizzle), alpha ----
        {
            const int n = w * 16 + col;
            const int swz = (n >> 1) & 3;
#pragma unroll
            for (int mt = 0; mt < 2; ++mt) {
                const int seg16 = mt * 2 + (q4 >> 1);
                *(half4*)((char*)&Ps[cur][n * 32] + ((seg16 ^ swz) * 16 + (q4 & 1) * 8)) = pk[mt];
            }
            if (q4 == 0) alph_s[cur][n] = al;
        }

        __syncthreads();   // drains V_it loads; Ps[cur]/alph visible; prev PV done

        // ---- prefetch iter it+1 (stays in flight across PV + next S/stats) ----
        if (it < 63) {
            const int mcn = mc + 32;
#pragma unroll
            for (int j = 0; j < 4; ++j) {
                const int c = w * 64 + j * 16 + vrow_l;
                const int s_log = (lane & 3) ^ ((c >> 1) & 3);
                __builtin_amdgcn_global_load_lds(
                    (g1_void*)&vp[(size_t)c * BN + mcn + s_log * 8],
                    (l3_void*)&vs[1 - cur][(w * 64 + j * 16) * 32], 16, 0, 0);
            }
#pragma unroll
            for (int mt = 0; mt < 2; ++mt)
                ak[mt] = *(const half8*)&kp[(size_t)(mcn + mt * 16 + col) * DQ + q4 * 8];
        }

        // ---- rescale O (skip when all alphas are exactly 1) ----
        float a0 = alph_s[cur][col32];
        float a1 = alph_s[cur][32 + col32];
        if (!__all((a0 == 1.0f) && (a1 == 1.0f))) {
#pragma unroll
            for (int ct = 0; ct < 2; ++ct)
#pragma unroll
                for (int r = 0; r < 16; ++r) {
                    acc[ct][0][r] *= a0;
                    acc[ct][1][r] *= a1;
                }
        }

        // ---- O += V P^T ----
        const int swz0 = (col32 >> 1) & 3;
        const int swz1 = ((32 + col32) >> 1) & 3;
#pragma unroll
        for (int ks = 0; ks < 2; ++ks) {
            const int seg = ks * 2 + h;
            half8 bp0 = *(const half8*)((char*)&Ps[cur][col32 * 32] + (seg ^ swz0) * 16);
            half8 bp1 = *(const half8*)((char*)&Ps[cur][(32 + col32) * 32] + (seg ^ swz1) * 16);
#pragma unroll
            for (int ct = 0; ct < 2; ++ct) {
                const int c = w * 64 + ct * 32 + col32;
                half8 av = *(const half8*)((char*)&vs[cur][c * 32] + ((seg ^ ((c >> 1) & 3)) * 16));
                acc[ct][0] = __builtin_amdgcn_mfma_f32_32x32x16_f16(av, bp0, acc[ct][0], 0, 0, 0);
                acc[ct][1] = __builtin_amdgcn_mfma_f32_32x32x16_f16(av, bp1, acc[ct][1], 0, 0, 0);
            }
        }
    }

    // ---- epilogue: unnormalized O (f16) + (m,l), m in log2 domain ----
    if (q4 == 0) {
        const int n = n0 + w * 16 + col;
        Ml[(size_t)(kh * 8 + b) * BN + n] = m_i;
        Ml[(size_t)(16 + kh * 8 + b) * BN + n] = l_i;
    }
    _Float16* Opp = Op + (size_t)(kh * 8 + b) * NCH * BN;
#pragma unroll
    for (int ct = 0; ct < 2; ++ct)
#pragma unroll
        for (int nt = 0; nt < 2; ++nt)
#pragma unroll
            for (int r = 0; r < 16; ++r) {
                int row = (r & 3) + 8 * (r >> 2) + 4 * h;
                int c = w * 64 + ct * 32 + row;
                Opp[(size_t)c * BN + n0 + nt * 32 + col32] = (_Float16)acc[ct][nt][r];
            }
}

// ---------------------------------------------------------------------------
// Combine (exp2 domain for m).
// ---------------------------------------------------------------------------
__global__ __launch_bounds__(256) void combine_kernel(
    const _Float16* __restrict__ Op, const float* __restrict__ Ml,
    const float* __restrict__ x, float* __restrict__ out)
{
    const int n = blockIdx.x * 256 + threadIdx.x;
    const int c0 = blockIdx.y * 16;
    const int b = blockIdx.z;

    const float m0 = Ml[(size_t)b * BN + n];
    const float m1 = Ml[(size_t)(8 + b) * BN + n];
    const float l0 = Ml[(size_t)(16 + b) * BN + n];
    const float l1 = Ml[(size_t)(24 + b) * BN + n];
    const float M = fmaxf(m0, m1);
    const float a0 = EXP2F(m0 - M);
    const float a1 = EXP2F(m1 - M);
    const float inv = 1.0f / (l0 * a0 + l1 * a1);
    const float f0 = a0 * inv;
    const float f1 = a1 * inv;

    const _Float16* Op0 = Op + (size_t)b * NCH * BN;
    const _Float16* Op1 = Op + (size_t)(8 + b) * NCH * BN;
#pragma unroll 4
    for (int ci = 0; ci < 16; ++ci) {
        const int c = c0 + ci;
        const size_t off = ((size_t)b * NCH + c) * BN + n;
        const size_t po = (size_t)c * BN + n;
        out[off] = (float)Op0[po] * f0 + (float)Op1[po] * f1 + x[off];
    }
}

extern "C" void kernel_launch(void* const* d_in, const int* in_sizes, int n_in,
                              void* d_out, int out_size, void* d_ws, size_t ws_size,
                              hipStream_t stream)
{
    const float* x  = (const float*)d_in[0];
    const float* Wq = (const float*)d_in[1];
    const float* bq = (const float*)d_in[2];
    const float* Wk = (const float*)d_in[3];
    const float* bk = (const float*)d_in[4];
    const float* Wv = (const float*)d_in[5];
    const float* bv = (const float*)d_in[6];
    float* out = (float*)d_out;

    _Float16* ws = (_Float16*)d_ws;
    _Float16* W16 = ws;                               // 81920 f16 (160 KB)
    _Float16* qT  = W16 + 81920;                      // 8*4096*32 f16 (2 MB)
    _Float16* kT  = qT + (size_t)8 * BN * DQ;         // 8*4096*32 f16 (2 MB)
    _Float16* vb  = kT + (size_t)8 * BN * DQ;         // 8*256*4096 f16 (16 MB)
    _Float16* Op  = vb + (size_t)8 * NCH * BN;        // 2*8*256*4096 f16 (32 MB)
    float*    Ml  = (float*)(Op + (size_t)2 * 8 * NCH * BN);  // 0.5 MB

    convert_w<<<dim3(80), 256, 0, stream>>>(Wq, Wk, Wv, W16);
    proj_kernel<<<dim3(32, 8), 512, 0, stream>>>(x, W16, bq, bk, bv, qT, kT, vb);
    flash_kernel<<<dim3(BN / 64, 2, 8), 256, 0, stream>>>(qT, kT, vb, Op, Ml);
    combine_kernel<<<dim3(16, 16, 8), 256, 0, stream>>>(Op, Ml, x, out);
}

// Round 7
// 271.120 us; speedup vs baseline: 1.0116x; 1.0116x over previous
//
#include <hip/hip_runtime.h>
#include <stdint.h>

#define BN 4096      // N = H*W
#define NCH 256      // C
#define DQ 32        // D = C/8

typedef _Float16 half8  __attribute__((ext_vector_type(8)));
typedef _Float16 half4  __attribute__((ext_vector_type(4)));
typedef float   floatx4  __attribute__((ext_vector_type(4)));
typedef float   floatx16 __attribute__((ext_vector_type(16)));

typedef __attribute__((address_space(1))) const void g1_void;
typedef __attribute__((address_space(3))) void l3_void;

#define LOG2E 1.44269504088896f
#define EXP2F(x) __builtin_amdgcn_exp2f(x)

// ---------------------------------------------------------------------------
// convert_w: cast Wq|Wk|Wv (fp32) into one concatenated f16 buffer.
// Wk is pre-scaled by log2(e) so S-scores land in the exp2 domain.
// ---------------------------------------------------------------------------
__global__ __launch_bounds__(256) void convert_w(
    const float* __restrict__ Wq, const float* __restrict__ Wk,
    const float* __restrict__ Wv, _Float16* __restrict__ W16)
{
    int e4 = (blockIdx.x * 256 + threadIdx.x) * 4;
    float4 v;
    if (e4 < 8192)        v = *(const float4*)&Wq[e4];
    else if (e4 < 16384) {
        v = *(const float4*)&Wk[e4 - 8192];
        v.x *= LOG2E; v.y *= LOG2E; v.z *= LOG2E; v.w *= LOG2E;
    }
    else                  v = *(const float4*)&Wv[e4 - 16384];
    half4 h = { (_Float16)v.x, (_Float16)v.y, (_Float16)v.z, (_Float16)v.w };
    *(half4*)&W16[e4] = h;
}

// ---------------------------------------------------------------------------
// MFMA projection (unchanged).
// ---------------------------------------------------------------------------
__global__ __launch_bounds__(512) void proj_kernel(
    const float* __restrict__ x, const _Float16* __restrict__ W16,
    const float* __restrict__ bq, const float* __restrict__ bk,
    const float* __restrict__ bv,
    _Float16* __restrict__ qT, _Float16* __restrict__ kT,
    _Float16* __restrict__ vb)
{
    const int t  = threadIdx.x;
    const int n0 = blockIdx.x * 128;
    const int b  = blockIdx.y;

    __shared__ __align__(16) _Float16 xTl[128 * 256];  // 64 KB

#pragma unroll
    for (int p = 0; p < 2; ++p) {
        const int kb = p * 128 + (t >> 5) * 8;
        const int n4 = (t & 31) * 4;
        float4 xr[8];
#pragma unroll
        for (int i = 0; i < 8; ++i)
            xr[i] = *(const float4*)&x[((size_t)b * NCH + kb + i) * BN + n0 + n4];
        const float* xf = (const float*)xr;
#pragma unroll
        for (int j = 0; j < 4; ++j) {
            const int n = n4 + j;
            half8 hv;
#pragma unroll
            for (int i = 0; i < 8; ++i) hv[i] = (_Float16)xf[i * 4 + j];
            const int phys = (kb >> 3) ^ ((n >> 2) & 31);
            *(half8*)&xTl[n * 256 + phys * 8] = hv;
        }
    }
    __syncthreads();

    const int lane  = t & 63;
    const int w     = t >> 6;
    const int col32 = lane & 31;
    const int h     = lane >> 5;
    const int nc    = w & 3;
    const int job   = w >> 2;

    const _Float16* Wq16 = W16;
    const _Float16* Wk16 = W16 + 8192;
    const _Float16* Wv16 = W16 + 16384;

#define XFRAG(ks) (*(const half8*)&xTl[(nc * 32 + col32) * 256 + \
        (((ks) * 2 + h) ^ (((nc * 32 + col32) >> 2) & 31)) * 8])

    if (job == 0) {
        const float bqv = bq[col32];
        const float bkv = bk[col32] * LOG2E;
        floatx16 aq, ak2;
#pragma unroll
        for (int r = 0; r < 16; ++r) { aq[r] = 0.0f; ak2[r] = 0.0f; }
#pragma unroll
        for (int ks = 0; ks < 16; ++ks) {
            half8 xa = XFRAG(ks);
            half8 wqf = *(const half8*)&Wq16[col32 * 256 + ks * 16 + h * 8];
            half8 wkf = *(const half8*)&Wk16[col32 * 256 + ks * 16 + h * 8];
            aq  = __builtin_amdgcn_mfma_f32_32x32x16_f16(xa, wqf, aq, 0, 0, 0);
            ak2 = __builtin_amdgcn_mfma_f32_32x32x16_f16(xa, wkf, ak2, 0, 0, 0);
        }
#pragma unroll
        for (int r = 0; r < 16; ++r) {
            const int n = n0 + nc * 32 + (r & 3) + 8 * (r >> 2) + 4 * h;
            qT[((size_t)b * BN + n) * DQ + col32] = (_Float16)(aq[r] + bqv);
            kT[((size_t)b * BN + n) * DQ + col32] = (_Float16)(ak2[r] + bkv);
        }
    }

    const int rg_lo = (job == 0) ? 0 : 3;
    const int rg_hi = (job == 0) ? 3 : 8;
    for (int rg = rg_lo; rg < rg_hi; ++rg) {
        floatx16 av;
#pragma unroll
        for (int r = 0; r < 16; ++r) av[r] = 0.0f;
#pragma unroll
        for (int ks = 0; ks < 16; ++ks) {
            half8 xb  = XFRAG(ks);
            half8 wvf = *(const half8*)&Wv16[(rg * 32 + col32) * 256 + ks * 16 + h * 8];
            av = __builtin_amdgcn_mfma_f32_32x32x16_f16(wvf, xb, av, 0, 0, 0);
        }
#pragma unroll
        for (int r = 0; r < 16; ++r) {
            const int c = rg * 32 + (r & 3) + 8 * (r >> 2) + 4 * h;
            vb[((size_t)b * NCH + c) * BN + n0 + nc * 32 + col32] =
                (_Float16)(av[r] + bv[c]);
        }
    }
#undef XFRAG
}

// ---------------------------------------------------------------------------
// MFMA flash attention, single-barrier pipelined K-loop.
// R7 fix: K register loads issued BEFORE V global_load_lds (vmcnt is an
// in-order counter -> waiting on K leaves the V loads in flight; issuing V
// first made every S wait an effective vmcnt(0), draining the pipeline).
// ---------------------------------------------------------------------------
__global__ __launch_bounds__(256, 3) void flash_kernel(
    const _Float16* __restrict__ qT, const _Float16* __restrict__ kT,
    const _Float16* __restrict__ vb,
    _Float16* __restrict__ Op, float* __restrict__ Ml)
{
    const int t    = threadIdx.x;
    const int lane = t & 63;
    const int w    = t >> 6;
    const int n0   = blockIdx.x * 64;
    const int kh   = blockIdx.y;
    const int b    = blockIdx.z;
    const int kbase = kh * 2048;

    __shared__ __align__(16) _Float16 vs[2][NCH * 32];  // 2 x 16 KB
    __shared__ __align__(16) _Float16 Ps[2][64 * 32];   // 2 x 4 KB
    __shared__ float alph_s[2][64];

    const int col   = lane & 15;
    const int q4    = lane >> 4;
    const int col32 = lane & 31;
    const int h     = lane >> 5;

    const _Float16* kp = kT + (size_t)b * BN * DQ;
    const _Float16* vp = vb + (size_t)b * NCH * BN;

    // persistent B_Q frag
    half8 bqf = *(const half8*)&qT[((size_t)b * BN + n0 + w * 16 + col) * DQ + q4 * 8];

    floatx16 acc[2][2];
#pragma unroll
    for (int ct = 0; ct < 2; ++ct)
#pragma unroll
        for (int nt = 0; nt < 2; ++nt)
#pragma unroll
            for (int r = 0; r < 16; ++r) acc[ct][nt][r] = 0.0f;

    float m_i = -1e30f, l_i = 0.0f;

    // V staging geometry: per call 64 lanes x 16B = 16 rows x 64B
    const int vrow_l = lane >> 2;                       // 0..15 row within call
    // prologue: K0 -> regs FIRST, then V0 -> vs[0]
    half8 ak[2];
#pragma unroll
    for (int mt = 0; mt < 2; ++mt)
        ak[mt] = *(const half8*)&kp[(size_t)(kbase + mt * 16 + col) * DQ + q4 * 8];
#pragma unroll
    for (int j = 0; j < 4; ++j) {
        const int c = w * 64 + j * 16 + vrow_l;
        const int s_log = (lane & 3) ^ ((c >> 1) & 3);
        __builtin_amdgcn_global_load_lds(
            (g1_void*)&vp[(size_t)c * BN + kbase + s_log * 8],
            (l3_void*)&vs[0][(w * 64 + j * 16) * 32], 16, 0, 0);
    }

    for (int it = 0; it < 64; ++it) {
        const int cur = it & 1;
        const int mc  = kbase + it * 32;

        // ---- S = K^T Q (exp2 domain) ----
        floatx4 sf[2];
#pragma unroll
        for (int mt = 0; mt < 2; ++mt) {
            floatx4 z = { 0.0f, 0.0f, 0.0f, 0.0f };
            sf[mt] = __builtin_amdgcn_mfma_f32_16x16x32_f16(ak[mt], bqf, z, 0, 0, 0);
        }

        // ---- online softmax stats ----
        float cmax = fmaxf(fmaxf(fmaxf(sf[0][0], sf[0][1]), fmaxf(sf[0][2], sf[0][3])),
                           fmaxf(fmaxf(sf[1][0], sf[1][1]), fmaxf(sf[1][2], sf[1][3])));
        cmax = fmaxf(cmax, __shfl_xor(cmax, 16));
        cmax = fmaxf(cmax, __shfl_xor(cmax, 32));
        float mn = fmaxf(m_i, cmax);
        float al = EXP2F(m_i - mn);
        float csum = 0.0f;
        half4 pk[2];
#pragma unroll
        for (int mt = 0; mt < 2; ++mt) {
            float p0 = EXP2F(sf[mt][0] - mn);
            float p1 = EXP2F(sf[mt][1] - mn);
            float p2 = EXP2F(sf[mt][2] - mn);
            float p3 = EXP2F(sf[mt][3] - mn);
            csum += p0 + p1 + p2 + p3;
            pk[mt] = (half4){ (_Float16)p0, (_Float16)p1, (_Float16)p2, (_Float16)p3 };
        }
        csum += __shfl_xor(csum, 16);
        csum += __shfl_xor(csum, 32);
        l_i = l_i * al + csum;
        m_i = mn;

        // ---- write Ps[cur] (seg16 ^ ((n>>1)&3) swizzle), alpha ----
        {
            const int n = w * 16 + col;
            const int swz = (n >> 1) & 3;
#pragma unroll
            for (int mt = 0; mt < 2; ++mt) {
                const int seg16 = mt * 2 + (q4 >> 1);
                *(half4*)((char*)&Ps[cur][n * 32] + ((seg16 ^ swz) * 16 + (q4 & 1) * 8)) = pk[mt];
            }
            if (q4 == 0) alph_s[cur][n] = al;
        }

        __syncthreads();   // drains V_it loads; Ps[cur]/alph visible; prev PV done

        // ---- prefetch iter it+1: K regs FIRST, then async V->LDS ----
        if (it < 63) {
            const int mcn = mc + 32;
#pragma unroll
            for (int mt = 0; mt < 2; ++mt)
                ak[mt] = *(const half8*)&kp[(size_t)(mcn + mt * 16 + col) * DQ + q4 * 8];
#pragma unroll
            for (int j = 0; j < 4; ++j) {
                const int c = w * 64 + j * 16 + vrow_l;
                const int s_log = (lane & 3) ^ ((c >> 1) & 3);
                __builtin_amdgcn_global_load_lds(
                    (g1_void*)&vp[(size_t)c * BN + mcn + s_log * 8],
                    (l3_void*)&vs[1 - cur][(w * 64 + j * 16) * 32], 16, 0, 0);
            }
        }

        // ---- rescale O (skip when all alphas are exactly 1) ----
        float a0 = alph_s[cur][col32];
        float a1 = alph_s[cur][32 + col32];
        if (!__all((a0 == 1.0f) && (a1 == 1.0f))) {
#pragma unroll
            for (int ct = 0; ct < 2; ++ct)
#pragma unroll
                for (int r = 0; r < 16; ++r) {
                    acc[ct][0][r] *= a0;
                    acc[ct][1][r] *= a1;
                }
        }

        // ---- O += V P^T ----
        const int swz0 = (col32 >> 1) & 3;
        const int swz1 = ((32 + col32) >> 1) & 3;
#pragma unroll
        for (int ks = 0; ks < 2; ++ks) {
            const int seg = ks * 2 + h;
            half8 bp0 = *(const half8*)((char*)&Ps[cur][col32 * 32] + (seg ^ swz0) * 16);
            half8 bp1 = *(const half8*)((char*)&Ps[cur][(32 + col32) * 32] + (seg ^ swz1) * 16);
#pragma unroll
            for (int ct = 0; ct < 2; ++ct) {
                const int c = w * 64 + ct * 32 + col32;
                half8 av = *(const half8*)((char*)&vs[cur][c * 32] + ((seg ^ ((c >> 1) & 3)) * 16));
                acc[ct][0] = __builtin_amdgcn_mfma_f32_32x32x16_f16(av, bp0, acc[ct][0], 0, 0, 0);
                acc[ct][1] = __builtin_amdgcn_mfma_f32_32x32x16_f16(av, bp1, acc[ct][1], 0, 0, 0);
            }
        }
    }

    // ---- epilogue: unnormalized O (f16) + (m,l), m in log2 domain ----
    if (q4 == 0) {
        const int n = n0 + w * 16 + col;
        Ml[(size_t)(kh * 8 + b) * BN + n] = m_i;
        Ml[(size_t)(16 + kh * 8 + b) * BN + n] = l_i;
    }
    _Float16* Opp = Op + (size_t)(kh * 8 + b) * NCH * BN;
#pragma unroll
    for (int ct = 0; ct < 2; ++ct)
#pragma unroll
        for (int nt = 0; nt < 2; ++nt)
#pragma unroll
            for (int r = 0; r < 16; ++r) {
                int row = (r & 3) + 8 * (r >> 2) + 4 * h;
                int c = w * 64 + ct * 32 + row;
                Opp[(size_t)c * BN + n0 + nt * 32 + col32] = (_Float16)acc[ct][nt][r];
            }
}

// ---------------------------------------------------------------------------
// Combine (exp2 domain for m).
// ---------------------------------------------------------------------------
__global__ __launch_bounds__(256) void combine_kernel(
    const _Float16* __restrict__ Op, const float* __restrict__ Ml,
    const float* __restrict__ x, float* __restrict__ out)
{
    const int n = blockIdx.x * 256 + threadIdx.x;
    const int c0 = blockIdx.y * 16;
    const int b = blockIdx.z;

    const float m0 = Ml[(size_t)b * BN + n];
    const float m1 = Ml[(size_t)(8 + b) * BN + n];
    const float l0 = Ml[(size_t)(16 + b) * BN + n];
    const float l1 = Ml[(size_t)(24 + b) * BN + n];
    const float M = fmaxf(m0, m1);
    const float a0 = EXP2F(m0 - M);
    const float a1 = EXP2F(m1 - M);
    const float inv = 1.0f / (l0 * a0 + l1 * a1);
    const float f0 = a0 * inv;
    const float f1 = a1 * inv;

    const _Float16* Op0 = Op + (size_t)b * NCH * BN;
    const _Float16* Op1 = Op + (size_t)(8 + b) * NCH * BN;
#pragma unroll 4
    for (int ci = 0; ci < 16; ++ci) {
        const int c = c0 + ci;
        const size_t off = ((size_t)b * NCH + c) * BN + n;
        const size_t po = (size_t)c * BN + n;
        out[off] = (float)Op0[po] * f0 + (float)Op1[po] * f1 + x[off];
    }
}

extern "C" void kernel_launch(void* const* d_in, const int* in_sizes, int n_in,
                              void* d_out, int out_size, void* d_ws, size_t ws_size,
                              hipStream_t stream)
{
    const float* x  = (const float*)d_in[0];
    const float* Wq = (const float*)d_in[1];
    const float* bq = (const float*)d_in[2];
    const float* Wk = (const float*)d_in[3];
    const float* bk = (const float*)d_in[4];
    const float* Wv = (const float*)d_in[5];
    const float* bv = (const float*)d_in[6];
    float* out = (float*)d_out;

    _Float16* ws = (_Float16*)d_ws;
    _Float16* W16 = ws;                               // 81920 f16 (160 KB)
    _Float16* qT  = W16 + 81920;                      // 8*4096*32 f16 (2 MB)
    _Float16* kT  = qT + (size_t)8 * BN * DQ;         // 8*4096*32 f16 (2 MB)
    _Float16* vb  = kT + (size_t)8 * BN * DQ;         // 8*256*4096 f16 (16 MB)
    _Float16* Op  = vb + (size_t)8 * NCH * BN;        // 2*8*256*4096 f16 (32 MB)
    float*    Ml  = (float*)(Op + (size_t)2 * 8 * NCH * BN);  // 0.5 MB

    convert_w<<<dim3(80), 256, 0, stream>>>(Wq, Wk, Wv, W16);
    proj_kernel<<<dim3(32, 8), 512, 0, stream>>>(x, W16, bq, bk, bv, qT, kT, vb);
    flash_kernel<<<dim3(BN / 64, 2, 8), 256, 0, stream>>>(qT, kT, vb, Op, Ml);
    combine_kernel<<<dim3(16, 16, 8), 256, 0, stream>>>(Op, Ml, x, out);
}

// Round 8
// 250.946 us; speedup vs baseline: 1.0929x; 1.0804x over previous
//
#include <hip/hip_runtime.h>
#include <stdint.h>

#define BN 4096      // N = H*W
#define NCH 256      // C
#define DQ 32        // D = C/8

typedef _Float16 half8  __attribute__((ext_vector_type(8)));
typedef _Float16 half4  __attribute__((ext_vector_type(4)));
typedef float   floatx4  __attribute__((ext_vector_type(4)));
typedef float   floatx16 __attribute__((ext_vector_type(16)));

typedef __attribute__((address_space(1))) const void g1_void;
typedef __attribute__((address_space(3))) void l3_void;

#define LOG2E 1.44269504088896f
#define EXP2F(x) __builtin_amdgcn_exp2f(x)
#define LOG2F(x) __builtin_amdgcn_logf(x)

// ---------------------------------------------------------------------------
// convert_w: cast Wq|Wk|Wv (fp32) into one concatenated f16 buffer.
// Wk pre-scaled by log2(e) so scores land in the exp2 domain.
// ---------------------------------------------------------------------------
__global__ __launch_bounds__(256) void convert_w(
    const float* __restrict__ Wq, const float* __restrict__ Wk,
    const float* __restrict__ Wv, _Float16* __restrict__ W16)
{
    int e4 = (blockIdx.x * 256 + threadIdx.x) * 4;
    float4 v;
    if (e4 < 8192)        v = *(const float4*)&Wq[e4];
    else if (e4 < 16384) {
        v = *(const float4*)&Wk[e4 - 8192];
        v.x *= LOG2E; v.y *= LOG2E; v.z *= LOG2E; v.w *= LOG2E;
    }
    else                  v = *(const float4*)&Wv[e4 - 16384];
    half4 h = { (_Float16)v.x, (_Float16)v.y, (_Float16)v.z, (_Float16)v.w };
    *(half4*)&W16[e4] = h;
}

// ---------------------------------------------------------------------------
// MFMA projection (unchanged from R4/R6).
// ---------------------------------------------------------------------------
__global__ __launch_bounds__(512) void proj_kernel(
    const float* __restrict__ x, const _Float16* __restrict__ W16,
    const float* __restrict__ bq, const float* __restrict__ bk,
    const float* __restrict__ bv,
    _Float16* __restrict__ qT, _Float16* __restrict__ kT,
    _Float16* __restrict__ vb)
{
    const int t  = threadIdx.x;
    const int n0 = blockIdx.x * 128;
    const int b  = blockIdx.y;

    __shared__ __align__(16) _Float16 xTl[128 * 256];  // 64 KB

#pragma unroll
    for (int p = 0; p < 2; ++p) {
        const int kb = p * 128 + (t >> 5) * 8;
        const int n4 = (t & 31) * 4;
        float4 xr[8];
#pragma unroll
        for (int i = 0; i < 8; ++i)
            xr[i] = *(const float4*)&x[((size_t)b * NCH + kb + i) * BN + n0 + n4];
        const float* xf = (const float*)xr;
#pragma unroll
        for (int j = 0; j < 4; ++j) {
            const int n = n4 + j;
            half8 hv;
#pragma unroll
            for (int i = 0; i < 8; ++i) hv[i] = (_Float16)xf[i * 4 + j];
            const int phys = (kb >> 3) ^ ((n >> 2) & 31);
            *(half8*)&xTl[n * 256 + phys * 8] = hv;
        }
    }
    __syncthreads();

    const int lane  = t & 63;
    const int w     = t >> 6;
    const int col32 = lane & 31;
    const int h     = lane >> 5;
    const int nc    = w & 3;
    const int job   = w >> 2;

    const _Float16* Wq16 = W16;
    const _Float16* Wk16 = W16 + 8192;
    const _Float16* Wv16 = W16 + 16384;

#define XFRAG(ks) (*(const half8*)&xTl[(nc * 32 + col32) * 256 + \
        (((ks) * 2 + h) ^ (((nc * 32 + col32) >> 2) & 31)) * 8])

    if (job == 0) {
        const float bqv = bq[col32];
        const float bkv = bk[col32] * LOG2E;
        floatx16 aq, ak2;
#pragma unroll
        for (int r = 0; r < 16; ++r) { aq[r] = 0.0f; ak2[r] = 0.0f; }
#pragma unroll
        for (int ks = 0; ks < 16; ++ks) {
            half8 xa = XFRAG(ks);
            half8 wqf = *(const half8*)&Wq16[col32 * 256 + ks * 16 + h * 8];
            half8 wkf = *(const half8*)&Wk16[col32 * 256 + ks * 16 + h * 8];
            aq  = __builtin_amdgcn_mfma_f32_32x32x16_f16(xa, wqf, aq, 0, 0, 0);
            ak2 = __builtin_amdgcn_mfma_f32_32x32x16_f16(xa, wkf, ak2, 0, 0, 0);
        }
#pragma unroll
        for (int r = 0; r < 16; ++r) {
            const int n = n0 + nc * 32 + (r & 3) + 8 * (r >> 2) + 4 * h;
            qT[((size_t)b * BN + n) * DQ + col32] = (_Float16)(aq[r] + bqv);
            kT[((size_t)b * BN + n) * DQ + col32] = (_Float16)(ak2[r] + bkv);
        }
    }

    const int rg_lo = (job == 0) ? 0 : 3;
    const int rg_hi = (job == 0) ? 3 : 8;
    for (int rg = rg_lo; rg < rg_hi; ++rg) {
        floatx16 av;
#pragma unroll
        for (int r = 0; r < 16; ++r) av[r] = 0.0f;
#pragma unroll
        for (int ks = 0; ks < 16; ++ks) {
            half8 xb  = XFRAG(ks);
            half8 wvf = *(const half8*)&Wv16[(rg * 32 + col32) * 256 + ks * 16 + h * 8];
            av = __builtin_amdgcn_mfma_f32_32x32x16_f16(wvf, xb, av, 0, 0, 0);
        }
#pragma unroll
        for (int r = 0; r < 16; ++r) {
            const int c = rg * 32 + (r & 3) + 8 * (r >> 2) + 4 * h;
            vb[((size_t)b * NCH + c) * BN + n0 + nc * 32 + col32] =
                (_Float16)(av[r] + bv[c]);
        }
    }
#undef XFRAG
}

// ---------------------------------------------------------------------------
// MFMA flash attention, key-split (runtime KPS). grid (64, nsplit, 8).
// R4-proven 64-key / 2-barrier loop body + exp2 domain + rescale-skip +
// K-before-V prefetch. Epilogue: O normalized by l (f16) + z = m + log2(l).
// ---------------------------------------------------------------------------
__global__ __launch_bounds__(256, 3) void flash_kernel(
    const _Float16* __restrict__ qT, const _Float16* __restrict__ kT,
    const _Float16* __restrict__ vb,
    _Float16* __restrict__ Op, float* __restrict__ Ml, int KPS)
{
    const int t    = threadIdx.x;
    const int lane = t & 63;
    const int w    = t >> 6;
    const int n0   = blockIdx.x * 64;
    const int kh   = blockIdx.y;
    const int b    = blockIdx.z;
    const int kbase = kh * KPS;
    const int iters = (min(KPS, BN - kbase)) >> 6;

    __shared__ __align__(16) _Float16 vs[NCH * 64];  // [c][seg^], 32 KB
    __shared__ __align__(16) _Float16 Ps[64 * 64];   // [n][pair^], 8 KB
    __shared__ float alph_s[64];
    __shared__ float l_s[64];

    const int col   = lane & 15;
    const int q4    = lane >> 4;
    const int col32 = lane & 31;
    const int h     = lane >> 5;

    const _Float16* kp = kT + (size_t)b * BN * DQ;
    const _Float16* vp = vb + (size_t)b * NCH * BN;

    // persistent B_Q frag
    half8 bqf = *(const half8*)&qT[((size_t)b * BN + n0 + w * 16 + col) * DQ + q4 * 8];

    floatx16 acc[2][2];
#pragma unroll
    for (int ct = 0; ct < 2; ++ct)
#pragma unroll
        for (int nt = 0; nt < 2; ++nt)
#pragma unroll
            for (int r = 0; r < 16; ++r) acc[ct][nt][r] = 0.0f;

    float m_i = -1e30f, l_i = 0.0f;

    const int sc_loc = lane >> 3;
    const int s_log  = (lane & 7) ^ (sc_loc & 7);
    // prologue: K0 regs first, then async V0 -> vs
    half8 ak[4];
#pragma unroll
    for (int mt = 0; mt < 4; ++mt)
        ak[mt] = *(const half8*)&kp[(size_t)(kbase + mt * 16 + col) * DQ + q4 * 8];
#pragma unroll
    for (int j = 0; j < 8; ++j) {
        const int c = w * 64 + j * 8 + sc_loc;
        __builtin_amdgcn_global_load_lds(
            (g1_void*)&vp[(size_t)c * BN + kbase + s_log * 8],
            (l3_void*)&vs[(w * 64 + j * 8) * 64], 16, 0, 0);
    }

    for (int it = 0; it < iters; ++it) {
        const int mc = kbase + it * 64;

        // ---- S = K^T Q (exp2 domain) ----
        floatx4 sf[4];
#pragma unroll
        for (int mt = 0; mt < 4; ++mt) {
            floatx4 z = { 0.0f, 0.0f, 0.0f, 0.0f };
            sf[mt] = __builtin_amdgcn_mfma_f32_16x16x32_f16(ak[mt], bqf, z, 0, 0, 0);
        }

        // ---- online softmax stats (16 scores/lane) ----
        float cmax = -1e30f;
#pragma unroll
        for (int mt = 0; mt < 4; ++mt)
#pragma unroll
            for (int r = 0; r < 4; ++r) cmax = fmaxf(cmax, sf[mt][r]);
        cmax = fmaxf(cmax, __shfl_xor(cmax, 16));
        cmax = fmaxf(cmax, __shfl_xor(cmax, 32));
        float mn = fmaxf(m_i, cmax);
        float al = EXP2F(m_i - mn);
        float csum = 0.0f;
        half4 pk[4];
#pragma unroll
        for (int mt = 0; mt < 4; ++mt) {
            float p0 = EXP2F(sf[mt][0] - mn);
            float p1 = EXP2F(sf[mt][1] - mn);
            float p2 = EXP2F(sf[mt][2] - mn);
            float p3 = EXP2F(sf[mt][3] - mn);
            csum += p0 + p1 + p2 + p3;
            pk[mt] = (half4){ (_Float16)p0, (_Float16)p1, (_Float16)p2, (_Float16)p3 };
        }
        csum += __shfl_xor(csum, 16);
        csum += __shfl_xor(csum, 32);
        l_i = l_i * al + csum;
        m_i = mn;

        // ---- write Ps (R4 swizzle), alpha ----
        {
            const int n = w * 16 + col;
#pragma unroll
            for (int mt = 0; mt < 4; ++mt) {
                const int p_log = 2 * mt + (q4 >> 1);
                const int p_phys = p_log ^ (n & 7);
                *(half4*)((char*)&Ps[n * 64] + p_phys * 16 + (q4 & 1) * 8) = pk[mt];
            }
            if (q4 == 0) alph_s[n] = al;
        }

        __syncthreads();   // barrier1: Ps/alpha visible; V_it loads drained

        // ---- rescale O (skip when all alphas exactly 1) ----
        float a0 = alph_s[col32];
        float a1 = alph_s[32 + col32];
        if (!__all((a0 == 1.0f) && (a1 == 1.0f))) {
#pragma unroll
            for (int ct = 0; ct < 2; ++ct)
#pragma unroll
                for (int r = 0; r < 16; ++r) {
                    acc[ct][0][r] *= a0;
                    acc[ct][1][r] *= a1;
                }
        }

        // ---- O += V P^T ----
#pragma unroll
        for (int ks = 0; ks < 4; ++ks) {
            const int p_log = 2 * ks + h;
            half8 bp0 = *(const half8*)((char*)&Ps[col32 * 64] + (p_log ^ (col32 & 7)) * 16);
            half8 bp1 = *(const half8*)((char*)&Ps[(32 + col32) * 64] + (p_log ^ (col32 & 7)) * 16);
#pragma unroll
            for (int ct = 0; ct < 2; ++ct) {
                const int c = w * 64 + ct * 32 + col32;
                half8 av = *(const half8*)((char*)&vs[c * 64] + ((p_log ^ (c & 7)) * 16));
                acc[ct][0] = __builtin_amdgcn_mfma_f32_32x32x16_f16(av, bp0, acc[ct][0], 0, 0, 0);
                acc[ct][1] = __builtin_amdgcn_mfma_f32_32x32x16_f16(av, bp1, acc[ct][1], 0, 0, 0);
            }
        }

        __syncthreads();   // barrier2: all waves done reading vs/Ps

        // ---- prefetch iter it+1: K regs first, then async V->LDS ----
        if (it + 1 < iters) {
            const int mcn = mc + 64;
#pragma unroll
            for (int mt = 0; mt < 4; ++mt)
                ak[mt] = *(const half8*)&kp[(size_t)(mcn + mt * 16 + col) * DQ + q4 * 8];
#pragma unroll
            for (int j = 0; j < 8; ++j) {
                const int c = w * 64 + j * 8 + sc_loc;
                __builtin_amdgcn_global_load_lds(
                    (g1_void*)&vp[(size_t)c * BN + mcn + s_log * 8],
                    (l3_void*)&vs[(w * 64 + j * 8) * 64], 16, 0, 0);
            }
        }
    }

    // ---- epilogue: normalized O (f16) + z = m + log2(l) ----
    if (q4 == 0) {
        const int n = w * 16 + col;
        l_s[n] = l_i;
        Ml[(size_t)(kh * 8 + b) * BN + n0 + n] = m_i + LOG2F(l_i);
    }
    __syncthreads();
    const float li0 = 1.0f / l_s[col32];
    const float li1 = 1.0f / l_s[32 + col32];

    _Float16* Opp = Op + (size_t)(kh * 8 + b) * NCH * BN;
#pragma unroll
    for (int ct = 0; ct < 2; ++ct)
#pragma unroll
        for (int nt = 0; nt < 2; ++nt) {
            const float li = nt ? li1 : li0;
#pragma unroll
            for (int r = 0; r < 16; ++r) {
                int row = (r & 3) + 8 * (r >> 2) + 4 * h;
                int c = w * 64 + ct * 32 + row;
                Opp[(size_t)c * BN + n0 + nt * 32 + col32] = (_Float16)(acc[ct][nt][r] * li);
            }
        }
}

// ---------------------------------------------------------------------------
// Combine: z-softmax merge of nsplit normalized partials + x residual.
// ---------------------------------------------------------------------------
__global__ __launch_bounds__(256) void combine_kernel(
    const _Float16* __restrict__ Op, const float* __restrict__ Ml,
    const float* __restrict__ x, float* __restrict__ out, int nsplit)
{
    const int n = blockIdx.x * 256 + threadIdx.x;
    const int c0 = blockIdx.y * 16;
    const int b = blockIdx.z;

    float z[3], f[3];
    float Z = -1e30f;
    for (int s = 0; s < nsplit; ++s) {
        z[s] = Ml[(size_t)(s * 8 + b) * BN + n];
        Z = fmaxf(Z, z[s]);
    }
    float lsum = 0.0f;
    for (int s = 0; s < nsplit; ++s) { f[s] = EXP2F(z[s] - Z); lsum += f[s]; }
    const float inv = 1.0f / lsum;
    for (int s = 0; s < nsplit; ++s) f[s] *= inv;

#pragma unroll 4
    for (int ci = 0; ci < 16; ++ci) {
        const int c = c0 + ci;
        const size_t off = ((size_t)b * NCH + c) * BN + n;
        const size_t po = (size_t)c * BN + n;
        float ov = 0.0f;
        for (int s = 0; s < nsplit; ++s)
            ov += (float)Op[(size_t)(s * 8 + b) * NCH * BN + po] * f[s];
        out[off] = ov + x[off];
    }
}

extern "C" void kernel_launch(void* const* d_in, const int* in_sizes, int n_in,
                              void* d_out, int out_size, void* d_ws, size_t ws_size,
                              hipStream_t stream)
{
    const float* x  = (const float*)d_in[0];
    const float* Wq = (const float*)d_in[1];
    const float* bq = (const float*)d_in[2];
    const float* Wk = (const float*)d_in[3];
    const float* bk = (const float*)d_in[4];
    const float* Wv = (const float*)d_in[5];
    const float* bv = (const float*)d_in[6];
    float* out = (float*)d_out;

    _Float16* ws = (_Float16*)d_ws;
    _Float16* W16 = ws;                               // 81920 f16
    _Float16* qT  = W16 + 81920;                      // 8*4096*32 f16 (2 MB)
    _Float16* kT  = qT + (size_t)8 * BN * DQ;         // 2 MB
    _Float16* vb  = kT + (size_t)8 * BN * DQ;         // 16 MB
    _Float16* Op  = vb + (size_t)8 * NCH * BN;        // nsplit*16 MB

    // choose split count by available workspace
    const size_t baseElems = 81920 + (size_t)2 * 8 * BN * DQ + (size_t)8 * NCH * BN;
    const size_t opElems3  = (size_t)3 * 8 * NCH * BN;
    const size_t mlBytes   = (size_t)24 * BN * sizeof(float);
    const size_t need3     = (baseElems + opElems3) * 2 + mlBytes + 256;
    const int nsplit = (ws_size >= need3) ? 3 : 2;
    const int KPS    = (nsplit == 3) ? 1408 : 2048;

    float* Ml = (float*)(Op + (size_t)nsplit * 8 * NCH * BN);

    convert_w<<<dim3(80), 256, 0, stream>>>(Wq, Wk, Wv, W16);
    proj_kernel<<<dim3(32, 8), 512, 0, stream>>>(x, W16, bq, bk, bv, qT, kT, vb);
    flash_kernel<<<dim3(64, nsplit, 8), 256, 0, stream>>>(qT, kT, vb, Op, Ml, KPS);
    combine_kernel<<<dim3(16, 16, 8), 256, 0, stream>>>(Op, Ml, x, out, nsplit);
}